// Round 2
// baseline (230.934 us; speedup 1.0000x reference)
//
#include <hip/hip_runtime.h>
#include <hip/hip_bf16.h>

#define N_TOK 1728      // 12*12*12
#define CDIM  64
#define NHEADS 32       // head_dim = 2
#define QTILES 27       // 1728 / 64
#define SCALE 0.70710678118654752f

// ---- dtype-adaptive load: flag=1 -> fp32 buffer, flag=0 -> bf16 buffer ----
__device__ __forceinline__ float ldin(const void* p, int i, int f32) {
    if (f32) return ((const float*)p)[i];
    union { unsigned int b; float f; } c;
    c.b = ((unsigned int)((const unsigned short*)p)[i]) << 16;
    return c.f;
}

// ---- Kernel 0: detect input dtype (1 wave) ----
// bf16 reinterpretation of fp32 data shows exp=0xFF / huge values quickly.
__global__ void detect_kernel(const void* x, int* flag) {
    int tid = threadIdx.x;
    union { unsigned int b; float f; } c;
    c.b = ((unsigned int)((const unsigned short*)x)[tid]) << 16;
    int bad = (((c.b >> 23) & 0xFF) == 0xFF) || (fabsf(c.f) > 1e10f);
    unsigned long long m = __ballot(bad);
    if (tid == 0) *flag = (m != 0ULL) ? 1 : 0;
}

// ================= FAST PATH (needs ~1.77 MB ws) =================
__global__ void qkv_kernel(const void* __restrict__ x,
                           const void* __restrict__ w_qkv,
                           float* __restrict__ Q, float* __restrict__ K,
                           float* __restrict__ V, const int* __restrict__ flagp) {
    int f = *flagp;
    int g  = blockIdx.x * blockDim.x + threadIdx.x;   // 0 .. 331775
    int n  = g % N_TOK;                               // coalesced over x
    int jj = g / N_TOK;                               // 0..191 wave-uniform
    float acc = 0.0f;
#pragma unroll 8
    for (int c = 0; c < CDIM; ++c)
        acc = fmaf(ldin(x, c * N_TOK + n, f), ldin(w_qkv, jj * CDIM + c, f), acc);
    int which = jj >> 6;
    int hd    = jj & 63;
    int idx   = (hd >> 1) * (N_TOK * 2) + n * 2 + (hd & 1);
    if (which == 0)      Q[idx] = acc * SCALE;
    else if (which == 1) K[idx] = acc;
    else                 V[idx] = acc;
}

__global__ void __launch_bounds__(64)
attn_fast(const float* __restrict__ Q, const float* __restrict__ K,
          const float* __restrict__ V, float* __restrict__ O) {
    __shared__ float2 Ks[N_TOK];
    __shared__ float2 Vs[N_TOK];
    int h  = blockIdx.x / QTILES;
    int n0 = (blockIdx.x % QTILES) * 64;
    const float2* Kf = (const float2*)(K + h * N_TOK * 2);
    const float2* Vf = (const float2*)(V + h * N_TOK * 2);
    for (int i = threadIdx.x; i < N_TOK; i += 64) { Ks[i] = Kf[i]; Vs[i] = Vf[i]; }
    __syncthreads();

    int n = n0 + threadIdx.x;
    float2 q = ((const float2*)(Q + h * N_TOK * 2))[n];
    float m = -1e30f;
#pragma unroll 4
    for (int j = 0; j < N_TOK; ++j) {
        float2 k = Ks[j];
        m = fmaxf(m, fmaf(q.x, k.x, q.y * k.y));
    }
    float l = 0.f, o0 = 0.f, o1 = 0.f;
#pragma unroll 4
    for (int j = 0; j < N_TOK; ++j) {
        float2 k = Ks[j];
        float2 v = Vs[j];
        float e = __expf(fmaf(q.x, k.x, q.y * k.y) - m);
        l += e; o0 = fmaf(e, v.x, o0); o1 = fmaf(e, v.y, o1);
    }
    float inv = 1.0f / l;
    O[n * CDIM + h * 2]     = o0 * inv;
    O[n * CDIM + h * 2 + 1] = o1 * inv;
}

// ========== INSURANCE PATH (ws only needs flag + 221 KB bf16 O) ==========
// Each block recomputes its head's K/V (and its 64 queries' Q) from x.
__global__ void __launch_bounds__(64)
attn_fused(const void* __restrict__ x, const void* __restrict__ w_qkv,
           __hip_bfloat16* __restrict__ O, const int* __restrict__ flagp) {
    __shared__ float2 Ks[N_TOK];     // 13824 B
    __shared__ float2 Vs[N_TOK];     // 13824 B
    __shared__ float  wr[6][CDIM];   // q0,q1,k0,k1,v0,v1 rows: 1536 B
    int f   = *flagp;
    int h   = blockIdx.x / QTILES;
    int qt  = blockIdx.x % QTILES;
    int tid = threadIdx.x;

    for (int idx = tid; idx < 6 * CDIM; idx += 64) {
        int r = idx >> 6, c = idx & 63;
        int row = (r < 2) ? (2 * h + r) : (r < 4) ? (64 + 2 * h + r - 2)
                                                  : (128 + 2 * h + r - 4);
        wr[r][c] = ldin(w_qkv, row * CDIM + c, f);
    }
    __syncthreads();

    float q0 = 0.f, q1 = 0.f;
    for (int s = 0; s < QTILES; ++s) {
        int n = s * 64 + tid;
        float k0 = 0.f, k1 = 0.f, v0 = 0.f, v1 = 0.f;
        if (s == qt) {            // wave-uniform branch
#pragma unroll 4
            for (int c = 0; c < CDIM; ++c) {
                float xv = ldin(x, c * N_TOK + n, f);   // coalesced lanes
                q0 = fmaf(xv, wr[0][c], q0); q1 = fmaf(xv, wr[1][c], q1);
                k0 = fmaf(xv, wr[2][c], k0); k1 = fmaf(xv, wr[3][c], k1);
                v0 = fmaf(xv, wr[4][c], v0); v1 = fmaf(xv, wr[5][c], v1);
            }
        } else {
#pragma unroll 4
            for (int c = 0; c < CDIM; ++c) {
                float xv = ldin(x, c * N_TOK + n, f);
                k0 = fmaf(xv, wr[2][c], k0); k1 = fmaf(xv, wr[3][c], k1);
                v0 = fmaf(xv, wr[4][c], v0); v1 = fmaf(xv, wr[5][c], v1);
            }
        }
        Ks[n] = make_float2(k0, k1);
        Vs[n] = make_float2(v0, v1);
    }
    q0 *= SCALE; q1 *= SCALE;
    __syncthreads();

    int n = qt * 64 + tid;
    float m = -1e30f;
#pragma unroll 4
    for (int j = 0; j < N_TOK; ++j) {
        float2 k = Ks[j];
        m = fmaxf(m, fmaf(q0, k.x, q1 * k.y));
    }
    float l = 0.f, o0 = 0.f, o1 = 0.f;
#pragma unroll 4
    for (int j = 0; j < N_TOK; ++j) {
        float2 k = Ks[j];
        float2 v = Vs[j];
        float e = __expf(fmaf(q0, k.x, q1 * k.y) - m);
        l += e; o0 = fmaf(e, v.x, o0); o1 = fmaf(e, v.y, o1);
    }
    float inv = 1.0f / l;
    O[n * CDIM + h * 2]     = __float2bfloat16(o0 * inv);
    O[n * CDIM + h * 2 + 1] = __float2bfloat16(o1 * inv);
}

// ---- Kernel 3: output projection (handles fp32 or bf16 O; out in flag dtype) ----
__global__ void proj_kernel(const void* __restrict__ O, int Ofp32,
                            const void* __restrict__ w_proj,
                            const void* __restrict__ b_proj,
                            void* __restrict__ out, const int* __restrict__ flagp) {
    int f  = *flagp;
    int g  = blockIdx.x * blockDim.x + threadIdx.x;  // 0 .. 110591
    int co = g & 63;
    int n  = g >> 6;
    float acc = ldin(b_proj, co, f);
#pragma unroll 8
    for (int ci = 0; ci < CDIM; ++ci) {
        float ov = Ofp32 ? ((const float*)O)[n * CDIM + ci]
                         : ldin(O, n * CDIM + ci, 0);
        acc = fmaf(ov, ldin(w_proj, co * CDIM + ci, f), acc);
    }
    if (f) ((float*)out)[g] = acc;
    else   ((__hip_bfloat16*)out)[g] = __float2bfloat16(acc);
}

extern "C" void kernel_launch(void* const* d_in, const int* in_sizes, int n_in,
                              void* d_out, int out_size, void* d_ws, size_t ws_size,
                              hipStream_t stream) {
    const void* x      = d_in[0];
    const void* w_qkv  = d_in[1];
    const void* w_proj = d_in[2];
    const void* b_proj = d_in[3];

    int*   flag = (int*)d_ws;
    char*  base = (char*)d_ws + 256;
    const size_t QKV_BYTES = (size_t)NHEADS * N_TOK * 2 * sizeof(float); // 442368
    bool fast = ws_size >= 256 + 4 * QKV_BYTES;   // ~1.77 MB

    detect_kernel<<<1, 64, 0, stream>>>(x, flag);

    if (fast) {
        float* Q = (float*)base;
        float* K = Q + NHEADS * N_TOK * 2;
        float* V = K + NHEADS * N_TOK * 2;
        float* O = V + NHEADS * N_TOK * 2;           // [1728][64] fp32
        qkv_kernel<<<1296, 256, 0, stream>>>(x, w_qkv, Q, K, V, flag);
        attn_fast<<<NHEADS * QTILES, 64, 0, stream>>>(Q, K, V, O);
        proj_kernel<<<432, 256, 0, stream>>>(O, 1, w_proj, b_proj, d_out, flag);
    } else {
        __hip_bfloat16* O = (__hip_bfloat16*)base;   // [1728][64] bf16, 221184 B
        attn_fused<<<NHEADS * QTILES, 64, 0, stream>>>(x, w_qkv, O, flag);
        proj_kernel<<<432, 256, 0, stream>>>(O, 0, w_proj, b_proj, d_out, flag);
    }
}

// Round 3
// 153.461 us; speedup vs baseline: 1.5048x; 1.5048x over previous
//
#include <hip/hip_runtime.h>
#include <hip/hip_bf16.h>

#define N_TOK  1728     // 12*12*12
#define CDIM   64
#define NHEADS 32       // head_dim = 2
#define QTILES 27       // 1728 / 64
#define SCALE  0.70710678118654752f   // 1/sqrt(2)
#define LOG2E  1.44269504088896340736f

// ---- dtype-adaptive load: f32=1 -> fp32 buffer, 0 -> bf16 buffer ----
// (uniform condition; LLVM loop-unswitches the hot loops on it)
__device__ __forceinline__ float ldin(const void* p, int i, int f32) {
    if (f32) return ((const float*)p)[i];
    union { unsigned int b; float f; } c;
    c.b = ((unsigned int)((const unsigned short*)p)[i]) << 16;
    return c.f;
}

// ---- Kernel 0: detect input dtype (1 wave) ----
__global__ void detect_kernel(const void* x, int* flag) {
    int tid = threadIdx.x;
    union { unsigned int b; float f; } c;
    c.b = ((unsigned int)((const unsigned short*)x)[tid]) << 16;
    int bad = (((c.b >> 23) & 0xFF) == 0xFF) || (fabsf(c.f) > 1e10f);
    unsigned long long m = __ballot(bad);
    if (tid == 0) *flag = (m != 0ULL) ? 1 : 0;
}

// ---- Kernel 1: QKV projection + w_proj transpose ----
// grid (27, 193), block 64. blockIdx.y = jj (uniform weight row -> s_loads).
// y==192 blocks transpose w_proj into fp32 wT[ci][co].
// Q[h][n][2] pre-scaled by SCALE*LOG2E; KV[h][n] = {k0,k1,v0,v1}.
__global__ void __launch_bounds__(64)
qkv_kernel(const void* __restrict__ x, const void* __restrict__ w_qkv,
           const void* __restrict__ w_proj,
           float* __restrict__ Q, float* __restrict__ KV,
           float* __restrict__ wT, const int* __restrict__ flagp) {
    int f   = *flagp;
    int tid = threadIdx.x;
    int jj  = blockIdx.y;
    if (jj == 192) {   // transpose duty: 27 blocks x 64 threads cover 4096 elems
        for (int e = blockIdx.x * 64 + tid; e < CDIM * CDIM; e += QTILES * 64)
            wT[e] = ldin(w_proj, (e & 63) * CDIM + (e >> 6), f);
        return;
    }
    int n = blockIdx.x * 64 + tid;            // coalesced over x
    float acc = 0.0f;
#pragma unroll 8
    for (int c = 0; c < CDIM; ++c)
        acc = fmaf(ldin(x, c * N_TOK + n, f), ldin(w_qkv, jj * CDIM + c, f), acc);
    int which = jj >> 6;
    int hd    = jj & 63;
    int h = hd >> 1, d = hd & 1;
    if (which == 0)
        Q[h * N_TOK * 2 + n * 2 + d] = acc * (SCALE * LOG2E);
    else
        KV[h * N_TOK * 4 + n * 4 + ((which == 1) ? d : 2 + d)] = acc;
}

// ---- Kernel 2: fused attention, single pass, no LDS ----
// grid (27, 32), block 64 = 1 wave, 1 query/thread.
// KV[j] is wave-uniform -> scalar/broadcast loads. exp2 (log2e folded into Q).
// No max-subtraction: |s'| << 127, fp32 range is ample; ratio is exact.
__global__ void __launch_bounds__(64)
attn_kernel(const float* __restrict__ Q, const float4* __restrict__ KV,
            __hip_bfloat16* __restrict__ O) {
    int h = blockIdx.y;
    int n = blockIdx.x * 64 + threadIdx.x;
    const float2 q = ((const float2*)(Q + h * N_TOK * 2))[n];
    const float4* __restrict__ KVh = KV + h * N_TOK;

    float l0 = 0.f, l1 = 0.f, o00 = 0.f, o01 = 0.f, o10 = 0.f, o11 = 0.f;
#pragma unroll 8
    for (int j = 0; j < N_TOK; j += 2) {
        float4 a = KVh[j];
        float4 b = KVh[j + 1];
        float ea = exp2f(fmaf(q.x, a.x, q.y * a.y));
        float eb = exp2f(fmaf(q.x, b.x, q.y * b.y));
        l0 += ea; o00 = fmaf(ea, a.z, o00); o01 = fmaf(ea, a.w, o01);
        l1 += eb; o10 = fmaf(eb, b.z, o10); o11 = fmaf(eb, b.w, o11);
    }
    float inv = 1.0f / (l0 + l1);
    __hip_bfloat162 o;
    o.x = __float2bfloat16((o00 + o10) * inv);
    o.y = __float2bfloat16((o01 + o11) * inv);
    *((__hip_bfloat162*)(O + n * CDIM + 2 * h)) = o;   // 4B-aligned (h-even pairs)
}

// ---- Kernel 3: output projection ----
// grid 1728, block 64: n = blockIdx, co = lane. O row uniform (scalar loads),
// wT[ci*64+co] coalesced fp32.
__global__ void __launch_bounds__(64)
proj_kernel(const __hip_bfloat16* __restrict__ Ob, const float* __restrict__ wT,
            const void* __restrict__ b_proj, void* __restrict__ out,
            const int* __restrict__ flagp) {
    int f  = *flagp;
    int n  = blockIdx.x;
    int co = threadIdx.x;
    float acc = ldin(b_proj, co, f);
#pragma unroll 8
    for (int ci = 0; ci < CDIM; ++ci) {
        float ov = ldin(Ob, n * CDIM + ci, 0);   // uniform bf16 row
        acc = fmaf(ov, wT[ci * CDIM + co], acc);
    }
    if (f) ((float*)out)[n * CDIM + co] = acc;
    else   ((__hip_bfloat16*)out)[n * CDIM + co] = __float2bfloat16(acc);
}

extern "C" void kernel_launch(void* const* d_in, const int* in_sizes, int n_in,
                              void* d_out, int out_size, void* d_ws, size_t ws_size,
                              hipStream_t stream) {
    const void* x      = d_in[0];
    const void* w_qkv  = d_in[1];
    const void* w_proj = d_in[2];
    const void* b_proj = d_in[3];

    // ws layout (total 1,564,928 B — fits the proven >=1.77 MB budget):
    int*   flag = (int*)d_ws;
    float* Q    = (float*)((char*)d_ws + 256);            // 442368 B
    float* KV   = Q  + NHEADS * N_TOK * 2;                // 884736 B, 16B-aligned
    float* wT   = KV + NHEADS * N_TOK * 4;                // 16384 B
    __hip_bfloat16* Ob = (__hip_bfloat16*)(wT + CDIM * CDIM); // 221184 B

    detect_kernel<<<1, 64, 0, stream>>>(x, flag);
    qkv_kernel   <<<dim3(QTILES, 193), 64, 0, stream>>>(x, w_qkv, w_proj, Q, KV, wT, flag);
    attn_kernel  <<<dim3(QTILES, NHEADS), 64, 0, stream>>>(Q, (const float4*)KV, Ob);
    proj_kernel  <<<N_TOK, 64, 0, stream>>>(Ob, wT, b_proj, d_out, flag);
}

// Round 4
// 121.771 us; speedup vs baseline: 1.8965x; 1.2602x over previous
//
#include <hip/hip_runtime.h>
#include <hip/hip_bf16.h>

#define N_TOK  1728     // 12*12*12
#define CDIM   64
#define NHEADS 32       // head_dim = 2
#define QTILES 27       // 1728 / 64
#define SCALE  0.70710678118654752f   // 1/sqrt(2)
#define LOG2E  1.44269504088896340736f
#define JW     8                       // waves per attn block (j-split factor)
#define JCHUNK (N_TOK / JW)            // 216 keys per wave

// ---- dtype-adaptive load: f32=1 -> fp32 buffer, 0 -> bf16 buffer ----
__device__ __forceinline__ float ldin(const void* p, int i, int f32) {
    if (f32) return ((const float*)p)[i];
    union { unsigned int b; float f; } c;
    c.b = ((unsigned int)((const unsigned short*)p)[i]) << 16;
    return c.f;
}

// ---- wave-local dtype sniff (call from 64-thread blocks, all lanes) ----
// fp32 data reinterpreted as bf16 pairs shows exp=0xFF / huge magnitudes.
__device__ __forceinline__ int sniff_f32(const void* x) {
    union { unsigned int b; float f; } c;
    c.b = ((unsigned int)((const unsigned short*)x)[threadIdx.x & 63]) << 16;
    int bad = (((c.b >> 23) & 0xFF) == 0xFF) || (fabsf(c.f) > 1e10f);
    return (__ballot(bad) != 0ULL) ? 1 : 0;
}

// ---- Kernel 1: QKV projection + w_proj transpose (dtype sniffed inline) ----
// grid (27, 193), block 64. blockIdx.y = jj (uniform weight row -> s_loads).
// y==192 blocks transpose w_proj into fp32 wT[ci][co].
// Q[h][n][2] pre-scaled by SCALE*LOG2E; KV[h][n] = {k0,k1,v0,v1}.
__global__ void __launch_bounds__(64)
qkv_kernel(const void* __restrict__ x, const void* __restrict__ w_qkv,
           const void* __restrict__ w_proj,
           float* __restrict__ Q, float* __restrict__ KV,
           float* __restrict__ wT) {
    int f   = sniff_f32(x);
    int tid = threadIdx.x;
    int jj  = blockIdx.y;
    if (jj == 192) {   // transpose duty: 27 blocks x 64 threads cover 4096 elems
        for (int e = blockIdx.x * 64 + tid; e < CDIM * CDIM; e += QTILES * 64)
            wT[e] = ldin(w_proj, (e & 63) * CDIM + (e >> 6), f);
        return;
    }
    int n = blockIdx.x * 64 + tid;            // coalesced over x
    float acc = 0.0f;
#pragma unroll 8
    for (int c = 0; c < CDIM; ++c)
        acc = fmaf(ldin(x, c * N_TOK + n, f), ldin(w_qkv, jj * CDIM + c, f), acc);
    int which = jj >> 6;
    int hd    = jj & 63;
    int h = hd >> 1, d = hd & 1;
    if (which == 0)
        Q[h * N_TOK * 2 + n * 2 + d] = acc * (SCALE * LOG2E);
    else
        KV[h * N_TOK * 4 + n * 4 + ((which == 1) ? d : 2 + d)] = acc;
}

// ---- Kernel 2: attention, 8-way j-split per block, batched loads ----
// grid (27, 32), block 512 = 8 waves. Wave w streams keys [w*216, (w+1)*216).
// No max-subtraction (|score*log2e| << 127): sums are associative -> j-split
// needs only an LDS add-reduce. Loads batched 8-deep for ILP.
__global__ void __launch_bounds__(512)
attn_kernel(const float* __restrict__ Q, const float4* __restrict__ KV,
            __hip_bfloat16* __restrict__ O) {
    __shared__ float red[JW][64][3];   // stride-3: worst 2-way bank alias (free)
    int h    = blockIdx.y;
    int tid  = threadIdx.x;
    int lane = tid & 63;
    int wav  = tid >> 6;
    int n    = blockIdx.x * 64 + lane;
    const float2 q = ((const float2*)(Q + h * N_TOK * 2))[n];  // pre-scaled
    const float4* __restrict__ KVp = KV + h * N_TOK + wav * JCHUNK;

    float l = 0.f, oa = 0.f, ob = 0.f;
    for (int g = 0; g < JCHUNK; g += 8) {   // 27 groups of 8 keys
        float4 k[8];
#pragma unroll
        for (int u = 0; u < 8; ++u) k[u] = KVp[g + u];   // 8 loads in flight
#pragma unroll
        for (int u = 0; u < 8; ++u) {
            float e = exp2f(fmaf(q.x, k[u].x, q.y * k[u].y));
            l  += e;
            oa  = fmaf(e, k[u].z, oa);
            ob  = fmaf(e, k[u].w, ob);
        }
    }
    red[wav][lane][0] = l;
    red[wav][lane][1] = oa;
    red[wav][lane][2] = ob;
    __syncthreads();
    if (wav == 0) {
        float L = 0.f, A = 0.f, B = 0.f;
#pragma unroll
        for (int w = 0; w < JW; ++w) {
            L += red[w][lane][0];
            A += red[w][lane][1];
            B += red[w][lane][2];
        }
        float inv = 1.0f / L;
        __hip_bfloat162 o;
        o.x = __float2bfloat16(A * inv);
        o.y = __float2bfloat16(B * inv);
        *((__hip_bfloat162*)(O + n * CDIM + 2 * h)) = o;  // 4B-aligned
    }
}

// ---- Kernel 3: output projection (dtype sniffed inline) ----
// grid 1728, block 64: n = blockIdx, co = lane. O row uniform (scalar loads),
// wT[ci*64+co] coalesced fp32.
__global__ void __launch_bounds__(64)
proj_kernel(const void* __restrict__ x,   // only for dtype sniff
            const __hip_bfloat16* __restrict__ Ob, const float* __restrict__ wT,
            const void* __restrict__ b_proj, void* __restrict__ out) {
    int f  = sniff_f32(x);
    int n  = blockIdx.x;
    int co = threadIdx.x;
    float acc = ldin(b_proj, co, f);
#pragma unroll 8
    for (int ci = 0; ci < CDIM; ++ci) {
        float ov = ldin(Ob, n * CDIM + ci, 0);   // uniform bf16 row
        acc = fmaf(ov, wT[ci * CDIM + co], acc);
    }
    if (f) ((float*)out)[n * CDIM + co] = acc;
    else   ((__hip_bfloat16*)out)[n * CDIM + co] = __float2bfloat16(acc);
}

extern "C" void kernel_launch(void* const* d_in, const int* in_sizes, int n_in,
                              void* d_out, int out_size, void* d_ws, size_t ws_size,
                              hipStream_t stream) {
    const void* x      = d_in[0];
    const void* w_qkv  = d_in[1];
    const void* w_proj = d_in[2];
    const void* b_proj = d_in[3];

    // ws layout (total ~1.56 MB — fits the proven budget):
    float* Q  = (float*)((char*)d_ws + 256);             // 442368 B
    float* KV = Q  + NHEADS * N_TOK * 2;                 // 884736 B, 16B-aligned
    float* wT = KV + NHEADS * N_TOK * 4;                 // 16384 B
    __hip_bfloat16* Ob = (__hip_bfloat16*)(wT + CDIM * CDIM); // 221184 B

    qkv_kernel <<<dim3(QTILES, 193), 64, 0, stream>>>(x, w_qkv, w_proj, Q, KV, wT);
    attn_kernel<<<dim3(QTILES, NHEADS), 512, 0, stream>>>(Q, (const float4*)KV, Ob);
    proj_kernel<<<N_TOK, 64, 0, stream>>>(x, Ob, wT, b_proj, d_out);
}